// Round 1
// baseline (36.961 us; speedup 1.0000x reference)
//
#include <hip/hip_runtime.h>

// CASSI base-mode forward on MI355X (gfx950).
// x:  (1, 31, 1024, 1024) f32, ca: (1, 1, 1024, 1024) f32
// out: (1, 1, 1024, 1054) f32
// Gather form: out[m][c] = sum_l x[l][m][c-l] * ca[m][c-l], l in [max(0,c-N+1), min(L-1,c)]
// Each x element is read exactly once from HBM -> memory-bound, ~138 MB total traffic.

constexpr int L = 31;
constexpr int M = 1024;
constexpr int N = 1024;
constexpr int NC = N + L - 1;          // 1054 output columns
constexpr int LSTRIDE = M * N;          // elements between successive l-slices

__global__ __launch_bounds__(256) void cassi_fwd_kernel(
    const float* __restrict__ x,
    const float* __restrict__ ca,
    float* __restrict__ out)
{
    const int c = blockIdx.x * blockDim.x + threadIdx.x;  // output column
    const int m = blockIdx.y;                             // row
    if (c >= NC) return;

    // Base pointers at (m, c); tap l reads offset l*LSTRIDE - l (x) and -l (ca).
    const float* xp  = x  + (long)m * N + c;
    const float* cap = ca + (long)m * N + c;

    float acc = 0.0f;

    if (c >= L - 1 && c < N) {
        // Full 31-tap window — uniform for interior blocks; unroll for MLP.
#pragma unroll
        for (int l = 0; l < L; ++l) {
            const long off = (long)l * LSTRIDE - l;
            acc = fmaf(xp[off], cap[-l], acc);
        }
    } else {
        // Edge columns: partial window.
        const int l_lo = (c > N - 1) ? (c - (N - 1)) : 0;
        const int l_hi = (c < L - 1) ? c : (L - 1);
        for (int l = l_lo; l <= l_hi; ++l) {
            const long off = (long)l * LSTRIDE - l;
            acc = fmaf(xp[off], cap[-l], acc);
        }
    }

    out[(long)m * NC + c] = acc;
}

extern "C" void kernel_launch(void* const* d_in, const int* in_sizes, int n_in,
                              void* d_out, int out_size, void* d_ws, size_t ws_size,
                              hipStream_t stream)
{
    const float* x  = (const float*)d_in[0];
    const float* ca = (const float*)d_in[1];
    float* out = (float*)d_out;

    dim3 block(256, 1, 1);
    dim3 grid((NC + 255) / 256, M, 1);   // (5, 1024)
    cassi_fwd_kernel<<<grid, block, 0, stream>>>(x, ca, out);
}

// Round 2
// 28.773 us; speedup vs baseline: 1.2846x; 1.2846x over previous
//
#include <hip/hip_runtime.h>

// CASSI base-mode forward on MI355X (gfx950).
// x:  (1, 31, 1024, 1024) f32, ca: (1, 1, 1024, 1024) f32
// out: (1, 1, 1024, 1054) f32
// Gather form: out[m][c] = sum_l x[l][m][c-l] * ca[m][c-l].
//
// Round-2 change: stage ca block-window (286 floats, zero-padded halo) in LDS.
// Rationale: ca (4 MB) == one XCD L2; streaming x (130 MB) evicts it, so the
// 31x ca re-read (~130 MB) was hitting HBM -> measured 3.7 TB/s "effective"
// was actually ~7.1 TB/s physical on 2x the compulsory bytes. LDS staging cuts
// ca HBM traffic to ~6 MB. Zero-padded halo makes the 31-tap loop uniform
// (no edge branch): out-of-window x reads stay inside the x allocation
// (offset l*2^20 + m*1024 + c - l >= 2^20 - 30 > 0 for l>=1) and are
// multiplied by 0.0f from the padded LDS.

constexpr int L = 31;
constexpr int M = 1024;
constexpr int N = 1024;
constexpr int NC = N + L - 1;            // 1054 output columns
constexpr int LSTRIDE = M * N;           // elements between successive l-slices
constexpr int BLK = 256;
constexpr int HALO = L - 1;              // 30
constexpr int CA_TILE = BLK + HALO;      // 286 staged ca columns

__global__ __launch_bounds__(256) void cassi_fwd_kernel(
    const float* __restrict__ x,
    const float* __restrict__ ca,
    float* __restrict__ out)
{
    __shared__ float sca[CA_TILE];

    const int tid = threadIdx.x;
    const int C0  = blockIdx.x * BLK;     // first output column of this block
    const int m   = blockIdx.y;           // row

    // Stage ca[m][C0-30 .. C0+255] into LDS, zero-padding out-of-range columns.
    for (int i = tid; i < CA_TILE; i += BLK) {
        const int col = C0 - HALO + i;
        sca[i] = (col >= 0 && col < N) ? ca[m * N + col] : 0.0f;
    }
    __syncthreads();

    const int c = C0 + tid;               // this thread's output column
    if (c >= NC) return;                  // (after the barrier)

    const float* xp = x + m * N + c;      // tap l reads xp[l*LSTRIDE - l]

    float acc = 0.0f;
#pragma unroll
    for (int l = 0; l < L; ++l) {
        acc = fmaf(xp[l * LSTRIDE - l], sca[tid + HALO - l], acc);
    }

    out[m * NC + c] = acc;
}

extern "C" void kernel_launch(void* const* d_in, const int* in_sizes, int n_in,
                              void* d_out, int out_size, void* d_ws, size_t ws_size,
                              hipStream_t stream)
{
    const float* x  = (const float*)d_in[0];
    const float* ca = (const float*)d_in[1];
    float* out = (float*)d_out;

    dim3 block(BLK, 1, 1);
    dim3 grid((NC + BLK - 1) / BLK, M, 1);   // (5, 1024)
    cassi_fwd_kernel<<<grid, block, 0, stream>>>(x, ca, out);
}